// Round 8
// baseline (512.747 us; speedup 1.0000x reference)
//
#include <hip/hip_runtime.h>
#include <math.h>

// Emulate XLA ReduceWindowRewriter's cumsum (what jnp.cumsum lowers to):
// reshape [n/16,16]; WITHIN-ROW SEQUENTIAL LEFT FOLD (naive reduce_window:
// C[j] = ((x0+x1)+x2)+...+xj — NOT Hillis-Steele; that detail was r7's
// residual); recursively scan row totals; add exclusive outer prefix (one
// f32 add per element). Recursion: 4M->262144->16384->1024->64->4(base:
// sequential fold). Then excl[i]=fl(C_i - sdt_i), expo=fl(excl_i-excl_lead),
// trans=exp(-expo), alpha=1-exp(-sdt), w=trans*alpha, ascending segment sums.
// All emulation arithmetic in __fadd_rn/__fsub_rn/__fmul_rn (no FMA/reassoc).

#define TPB 256

__device__ __forceinline__ float sdt_at(const float* __restrict__ ts,
                                        const float* __restrict__ te,
                                        const float* __restrict__ sg, int i) {
    float dt = __fsub_rn(te[i], ts[i]);   // ref's two f32 roundings
    return __fmul_rn(sg[i], dt);
}

__global__ void p0_init(int* __restrict__ starts, int* __restrict__ ends, int n_rays) {
    int i = blockIdx.x * blockDim.x + threadIdx.x;
    if (i < n_rays) { starts[i] = 0; ends[i] = 0; }
}

__global__ void find_bounds(const int* __restrict__ ri, int S,
                            int* __restrict__ starts, int* __restrict__ ends) {
    int i = blockIdx.x * blockDim.x + threadIdx.x;
    if (i >= S) return;
    int r = ri[i];
    if (i == 0 || ri[i - 1] != r) starts[r] = i;
    if (i == S - 1 || ri[i + 1] != r) ends[r] = i + 1;
}

// Level 0: per-thread sequential fold of 16 sdt values -> block total only.
__global__ void k_seq0(const float* __restrict__ ts, const float* __restrict__ te,
                       const float* __restrict__ sg, int S, float* __restrict__ T0) {
    int g = blockIdx.x * blockDim.x + threadIdx.x;
    if (g >= (S >> 4)) return;
    int base = g << 4;
    float acc = 0.0f;
    #pragma unroll
    for (int j = 0; j < 16; ++j) acc = __fadd_rn(acc, sdt_at(ts, te, sg, base + j));
    T0[g] = acc;
}

// Generic level: sequential fold within each 16-row; store full scan + totals.
__global__ void k_seq(const float* __restrict__ A, int n,
                      float* __restrict__ s_out, float* __restrict__ T_out) {
    int g = blockIdx.x * blockDim.x + threadIdx.x;
    if (g >= (n >> 4)) return;
    int base = g << 4;
    float acc = 0.0f;
    #pragma unroll
    for (int j = 0; j < 16; ++j) {
        acc = __fadd_rn(acc, A[base + j]);
        s_out[base + j] = acc;
    }
    T_out[g] = acc;
}

// Top: scan of 64 = 4 rows of 16 (sequential folds) + base fold of 4 totals,
// then combine. Single thread — trivial work.
__global__ void k_top64(const float* __restrict__ T3, float* __restrict__ C4) {
    float s4[64], T4[4];
    for (int r = 0; r < 4; ++r) {
        float acc = 0.0f;
        for (int j = 0; j < 16; ++j) {
            acc = __fadd_rn(acc, T3[r * 16 + j]);
            s4[r * 16 + j] = acc;
        }
        T4[r] = acc;
    }
    float C5[4];
    float c = 0.0f;
    for (int r = 0; r < 4; ++r) { c = __fadd_rn(c, T4[r]); C5[r] = c; }
    for (int j = 0; j < 64; ++j) {
        int r = j >> 4;
        C4[j] = r ? __fadd_rn(s4[j], C5[r - 1]) : s4[j];
    }
}

// Combine: C_out[j] = fl(s_in[j] + Cup[row-1])  (row 0: identity).
__global__ void k_comb(const float* __restrict__ s_in, const float* __restrict__ Cup,
                       float* __restrict__ C_out, int n) {
    int j = blockIdx.x * blockDim.x + threadIdx.x;
    if (j >= n) return;
    int r = j >> 4;
    float v = s_in[j];
    C_out[j] = r ? __fadd_rn(v, Cup[r - 1]) : v;
}

// Level 0 pass B: refold 16 sdt, add outer carry, subtract x -> excl.
__global__ void k_excl(const float* __restrict__ ts, const float* __restrict__ te,
                       const float* __restrict__ sg, int S,
                       const float* __restrict__ C1, float* __restrict__ excl) {
    int g = blockIdx.x * blockDim.x + threadIdx.x;
    if (g >= (S >> 4)) return;
    int base = g << 4;
    float carry = g ? C1[g - 1] : 0.0f;
    float acc = 0.0f;
    #pragma unroll
    for (int j = 0; j < 16; ++j) {
        float x = sdt_at(ts, te, sg, base + j);
        acc = __fadd_rn(acc, x);
        float Ci = g ? __fadd_rn(acc, carry) : acc;   // one combine add, like ref
        excl[base + j] = __fsub_rn(Ci, x);
    }
}

__global__ void render(const float* __restrict__ ts, const float* __restrict__ te,
                       const float* __restrict__ sg, const float* __restrict__ hdr,
                       const float* __restrict__ excl,
                       const int* __restrict__ starts, const int* __restrict__ ends,
                       float* __restrict__ out, int n_rays) {
    int r = blockIdx.x * blockDim.x + threadIdx.x;
    if (r >= n_rays) return;
    int s = starts[r], e = ends[r];
    float el = (s < e) ? excl[s] : 0.0f;
    float opac = 0.0f, cr = 0.0f, cg = 0.0f, cb = 0.0f;
    for (int i = s; i < e; ++i) {
        float x     = sdt_at(ts, te, sg, i);
        float expo  = __fsub_rn(excl[i], el);
        float trans = __expf(-expo);
        float alpha = __fsub_rn(1.0f, __expf(-x));
        float w     = __fmul_rn(trans, alpha);
        opac = __fadd_rn(opac, w);
        cr = __fadd_rn(cr, __fmul_rn(w, hdr[3 * i + 0]));
        cg = __fadd_rn(cg, __fmul_rn(w, hdr[3 * i + 1]));
        cb = __fadd_rn(cb, __fmul_rn(w, hdr[3 * i + 2]));
    }
    reinterpret_cast<float4*>(out)[r] = make_float4(opac, cr, cg, cb);
}

extern "C" void kernel_launch(void* const* d_in, const int* in_sizes, int n_in,
                              void* d_out, int out_size, void* d_ws, size_t ws_size,
                              hipStream_t stream) {
    const float* ts  = (const float*)d_in[0];
    const float* te  = (const float*)d_in[1];
    const float* sg  = (const float*)d_in[2];
    const float* hdr = (const float*)d_in[3];
    const int*   ri  = (const int*)d_in[4];
    const int S      = in_sizes[0];          // 4194304 = 2^22
    const int n_rays = out_size / 4;
    const int N1 = S  >> 4;                  // 262144
    const int N2 = N1 >> 4;                  // 16384
    const int N3 = N2 >> 4;                  // 1024
    const int N4 = N3 >> 4;                  // 64

    char* w = (char*)d_ws;
    auto alloc = [&](size_t bytes) { char* p = w; w += (bytes + 255) & ~255ULL; return p; };
    float* T0   = (float*)alloc((size_t)N1 * 4);
    float* s1   = (float*)alloc((size_t)N1 * 4);
    float* C1   = (float*)alloc((size_t)N1 * 4);
    float* T1   = (float*)alloc((size_t)N2 * 4);
    float* s2   = (float*)alloc((size_t)N2 * 4);
    float* C2   = (float*)alloc((size_t)N2 * 4);
    float* T2   = (float*)alloc((size_t)N3 * 4);
    float* s3   = (float*)alloc((size_t)N3 * 4);
    float* C3   = (float*)alloc((size_t)N3 * 4);
    float* T3   = (float*)alloc((size_t)N4 * 4);
    float* C4   = (float*)alloc((size_t)N4 * 4);
    float* excl = (float*)alloc((size_t)S * 4);
    int*  starts = (int*)alloc((size_t)n_rays * 4);
    int*  ends   = (int*)alloc((size_t)n_rays * 4);

    p0_init    <<<dim3((n_rays + TPB - 1) / TPB), dim3(TPB), 0, stream>>>(starts, ends, n_rays);
    k_seq0     <<<dim3((N1 + TPB - 1) / TPB), dim3(TPB), 0, stream>>>(ts, te, sg, S, T0);
    k_seq      <<<dim3((N2 + TPB - 1) / TPB), dim3(TPB), 0, stream>>>(T0, N1, s1, T1);
    k_seq      <<<dim3((N3 + TPB - 1) / TPB), dim3(TPB), 0, stream>>>(T1, N2, s2, T2);
    k_seq      <<<dim3((N4 + TPB - 1) / TPB), dim3(TPB), 0, stream>>>(T2, N3, s3, T3);
    k_top64    <<<dim3(1), dim3(1), 0, stream>>>(T3, C4);
    k_comb     <<<dim3((N3 + TPB - 1) / TPB), dim3(TPB), 0, stream>>>(s3, C4, C3, N3);
    k_comb     <<<dim3((N2 + TPB - 1) / TPB), dim3(TPB), 0, stream>>>(s2, C3, C2, N2);
    k_comb     <<<dim3((N1 + TPB - 1) / TPB), dim3(TPB), 0, stream>>>(s1, C2, C1, N1);
    k_excl     <<<dim3((N1 + TPB - 1) / TPB), dim3(TPB), 0, stream>>>(ts, te, sg, S, C1, excl);
    find_bounds<<<dim3((S + TPB - 1) / TPB), dim3(TPB), 0, stream>>>(ri, S, starts, ends);
    render     <<<dim3((n_rays + TPB - 1) / TPB), dim3(TPB), 0, stream>>>(
        ts, te, sg, hdr, excl, starts, ends, (float*)d_out, n_rays);
}

// Round 9
// 213.143 us; speedup vs baseline: 2.4056x; 2.4056x over previous
//
#include <hip/hip_runtime.h>

// NeRF render, numerics contract (frozen from r8, PASSED):
//   sdt_i = fmul(sg, fsub(te,ts));  blocked-16 XLA cumsum:
//   s1[g] = within-16 fold of T0 (T0[g] = fold16 of sdt);  upper recursion
//   16384->1024->64->4 sequential folds + combine adds -> C2[16384];
//   C1[j] = (j>>4)? fadd(s1[j], C2[(j>>4)-1]) : s1[j];
//   C_i = g? fadd(fold16_incl(i), C1[g-1]) : fold16_incl(i);
//   excl_i = fsub(C_i, sdt_i);  expo = fsub(excl_i, el[ray]);
//   w = fmul(exp(-expo), fsub(1, exp(-sdt_i))).
// r8 perf post-mortem: ray-major render fetched 1.22 GB (10x ideal) - lanes
// stride ~128B, L1/L2 thrash. This round: sample-major render, fully
// coalesced, excl fused in-block (LDS fold16), segmented scan + atomics
// for segment sums. 5 dispatches.

#define TPB 256

__device__ __forceinline__ float sdt_c(float tsv, float tev, float sgv) {
    return __fmul_rn(sgv, __fsub_rn(tev, tsv));
}

// zero out[n_rays][4]
__global__ void k_init(float4* __restrict__ out4, int n_rays) {
    int i = blockIdx.x * blockDim.x + threadIdx.x;
    if (i < n_rays) out4[i] = make_float4(0.f, 0.f, 0.f, 0.f);
}

// thread = one 16-group: materialize sdt, fold16 -> T0 (LDS), then
// within-16 fold of T0 row -> s1, T1.   grid: (S>>4)/TPB blocks.
__global__ void k_bottom(const float* __restrict__ ts, const float* __restrict__ te,
                         const float* __restrict__ sg, int S,
                         float* __restrict__ sdt, float* __restrict__ s1,
                         float* __restrict__ T1) {
    __shared__ float st[TPB];
    int t = threadIdx.x;
    int g = blockIdx.x * TPB + t;            // group index < S>>4
    const float4* ts4 = (const float4*)ts;
    const float4* te4 = (const float4*)te;
    const float4* sg4 = (const float4*)sg;
    float4* sdt4 = (float4*)sdt;
    float acc = 0.0f;
    #pragma unroll
    for (int k = 0; k < 4; ++k) {
        float4 a = ts4[g * 4 + k], b = te4[g * 4 + k], c = sg4[g * 4 + k];
        float4 xo;
        xo.x = sdt_c(a.x, b.x, c.x);
        xo.y = sdt_c(a.y, b.y, c.y);
        xo.z = sdt_c(a.z, b.z, c.z);
        xo.w = sdt_c(a.w, b.w, c.w);
        acc = __fadd_rn(acc, xo.x);
        acc = __fadd_rn(acc, xo.y);
        acc = __fadd_rn(acc, xo.z);
        acc = __fadd_rn(acc, xo.w);
        sdt4[g * 4 + k] = xo;
    }
    st[t] = acc;                              // T0[g]
    __syncthreads();
    float acc2 = 0.0f;
    int b16 = t & ~15;
    for (int j = 0; j <= (t & 15); ++j) acc2 = __fadd_rn(acc2, st[b16 + j]);
    s1[g] = acc2;
    if ((t & 15) == 15) T1[g >> 4] = acc2;
}

// single block, 1024 threads: scan T1[16384] through levels 2..base -> C2.
__global__ void k_mid(const float* __restrict__ T1, float* __restrict__ C2) {
    __shared__ float T2sh[1024];
    __shared__ float s3sh[1024];   // becomes C3 in place
    __shared__ float s4sh[64];     // becomes C4 in place
    __shared__ float T3sh[64];
    __shared__ float T4sh[4];
    __shared__ float C5sh[4];
    int t = threadIdx.x;
    const float4* T14 = (const float4*)T1;
    float s2l[16];
    float acc = 0.0f;
    #pragma unroll
    for (int k = 0; k < 4; ++k) {
        float4 v = T14[t * 4 + k];
        acc = __fadd_rn(acc, v.x); s2l[k * 4 + 0] = acc;
        acc = __fadd_rn(acc, v.y); s2l[k * 4 + 1] = acc;
        acc = __fadd_rn(acc, v.z); s2l[k * 4 + 2] = acc;
        acc = __fadd_rn(acc, v.w); s2l[k * 4 + 3] = acc;
    }
    T2sh[t] = acc;
    __syncthreads();
    if (t < 64) {                  // level 3
        float a3 = 0.0f;
        for (int j = 0; j < 16; ++j) { a3 = __fadd_rn(a3, T2sh[t * 16 + j]); s3sh[t * 16 + j] = a3; }
        T3sh[t] = a3;
    }
    __syncthreads();
    if (t < 4) {                   // level 4
        float a4 = 0.0f;
        for (int j = 0; j < 16; ++j) { a4 = __fadd_rn(a4, T3sh[t * 16 + j]); s4sh[t * 16 + j] = a4; }
        T4sh[t] = a4;
    }
    __syncthreads();
    if (t == 0) {                  // base fold of 4
        float c = 0.0f;
        for (int r = 0; r < 4; ++r) { c = __fadd_rn(c, T4sh[r]); C5sh[r] = c; }
    }
    __syncthreads();
    if (t < 64) {                  // C4 in place
        int r = t >> 4;
        float v4 = s4sh[t];
        s4sh[t] = r ? __fadd_rn(v4, C5sh[r - 1]) : v4;
    }
    __syncthreads();
    {                              // C3 in place (each thread own index)
        int r = t >> 4;
        float v3 = s3sh[t];
        float c3 = r ? __fadd_rn(v3, s4sh[r - 1]) : v3;
        s3sh[t] = c3;
    }
    __syncthreads();
    float c3m = t ? s3sh[t - 1] : 0.0f;   // C3[t-1]
    float4* C24 = (float4*)C2;
    #pragma unroll
    for (int k = 0; k < 4; ++k) {
        float4 o;
        o.x = t ? __fadd_rn(s2l[k * 4 + 0], c3m) : s2l[k * 4 + 0];
        o.y = t ? __fadd_rn(s2l[k * 4 + 1], c3m) : s2l[k * 4 + 1];
        o.z = t ? __fadd_rn(s2l[k * 4 + 2], c3m) : s2l[k * 4 + 2];
        o.w = t ? __fadd_rn(s2l[k * 4 + 3], c3m) : s2l[k * 4 + 3];
        C24[t * 4 + k] = o;
    }
}

// per-sample head detection -> el[ray] = excl at segment head.
__global__ void k_heads(const int* __restrict__ ri, const float* __restrict__ sdt,
                        const float* __restrict__ s1, const float* __restrict__ C2,
                        int S, float* __restrict__ el) {
    int i = blockIdx.x * blockDim.x + threadIdx.x;
    if (i >= S) return;
    int r = ri[i];
    if (i != 0 && ri[i - 1] == r) return;
    int g = i >> 4, b = g << 4, l = i & 15;
    float acc = 0.0f, x = 0.0f;
    for (int j = 0; j <= l; ++j) { x = sdt[b + j]; acc = __fadd_rn(acc, x); }
    float Ci = acc;
    if (g) {
        int j = g - 1;
        float cj = (j >> 4) ? __fadd_rn(s1[j], C2[(j >> 4) - 1]) : s1[j];
        Ci = __fadd_rn(acc, cj);
    }
    el[r] = __fsub_rn(Ci, x);
}

// sample-major render: coalesced reads, in-block fold16 via LDS, segmented
// scan of (w, w*hdr), atomicAdd per in-block segment tail.
__global__ void k_render(const int* __restrict__ ri, const float* __restrict__ sdt,
                         const float* __restrict__ s1, const float* __restrict__ C2,
                         const float* __restrict__ el, const float* __restrict__ hdr,
                         int S, float* __restrict__ out) {
    __shared__ float sxf[TPB];
    __shared__ int sr[TPB];
    __shared__ float4 sv[TPB];
    __shared__ int sfl[TPB];
    int t = threadIdx.x;
    int i = blockIdx.x * TPB + t;
    bool valid = i < S;
    float x = valid ? sdt[i] : 0.0f;
    int r = valid ? ri[i] : (-1 - t);
    sxf[t] = x; sr[t] = r;
    __syncthreads();
    float acc = 0.0f;
    int b16 = t & ~15;
    for (int j = 0; j <= (t & 15); ++j) acc = __fadd_rn(acc, sxf[b16 + j]);
    int g = i >> 4;
    float Ci = acc;
    if (g) {
        int j = g - 1;
        float cj = (j >> 4) ? __fadd_rn(s1[j], C2[(j >> 4) - 1]) : s1[j];
        Ci = __fadd_rn(acc, cj);
    }
    float excl = __fsub_rn(Ci, x);
    float w = 0.0f, hr = 0.0f, hg = 0.0f, hb = 0.0f;
    if (valid) {
        float expo  = __fsub_rn(excl, el[r]);
        float trans = __expf(-expo);
        float alpha = __fsub_rn(1.0f, __expf(-x));
        w  = __fmul_rn(trans, alpha);
        hr = hdr[3 * i + 0]; hg = hdr[3 * i + 1]; hb = hdr[3 * i + 2];
    }
    float4 myv = make_float4(w, __fmul_rn(w, hr), __fmul_rn(w, hg), __fmul_rn(w, hb));
    int myf = (t == 0) || (sr[t - 1] != r);
    sv[t] = myv; sfl[t] = myf;
    __syncthreads();
    #pragma unroll
    for (int s = 1; s < TPB; s <<= 1) {
        float4 pv = make_float4(0.f, 0.f, 0.f, 0.f);
        int pf = 1;
        if (t >= s) { pv = sv[t - s]; pf = sfl[t - s]; }
        __syncthreads();
        if (t >= s && !myf) {
            myv.x += pv.x; myv.y += pv.y; myv.z += pv.z; myv.w += pv.w;
            myf |= pf;
        }
        sv[t] = myv; sfl[t] = myf;
        __syncthreads();
    }
    bool tail = valid && (t == TPB - 1 || sr[t + 1] != r);
    if (tail) {
        float* o = out + 4 * r;
        atomicAdd(o + 0, myv.x);
        atomicAdd(o + 1, myv.y);
        atomicAdd(o + 2, myv.z);
        atomicAdd(o + 3, myv.w);
    }
}

extern "C" void kernel_launch(void* const* d_in, const int* in_sizes, int n_in,
                              void* d_out, int out_size, void* d_ws, size_t ws_size,
                              hipStream_t stream) {
    const float* ts  = (const float*)d_in[0];
    const float* te  = (const float*)d_in[1];
    const float* sg  = (const float*)d_in[2];
    const float* hdr = (const float*)d_in[3];
    const int*   ri  = (const int*)d_in[4];
    const int S      = in_sizes[0];          // 4194304 = 2^22
    const int n_rays = out_size / 4;
    const int N1 = S >> 4;                   // 262144
    const int N2 = N1 >> 4;                  // 16384

    char* w = (char*)d_ws;
    auto alloc = [&](size_t bytes) { char* p = w; w += (bytes + 255) & ~255ULL; return p; };
    float* sdt = (float*)alloc((size_t)S * 4);
    float* s1  = (float*)alloc((size_t)N1 * 4);
    float* T1  = (float*)alloc((size_t)N2 * 4);
    float* C2  = (float*)alloc((size_t)N2 * 4);
    float* el  = (float*)alloc((size_t)n_rays * 4);

    k_init  <<<dim3((n_rays + TPB - 1) / TPB), dim3(TPB), 0, stream>>>((float4*)d_out, n_rays);
    k_bottom<<<dim3(N1 / TPB), dim3(TPB), 0, stream>>>(ts, te, sg, S, sdt, s1, T1);
    k_mid   <<<dim3(1), dim3(1024), 0, stream>>>(T1, C2);
    k_heads <<<dim3((S + TPB - 1) / TPB), dim3(TPB), 0, stream>>>(ri, sdt, s1, C2, S, el);
    k_render<<<dim3((S + TPB - 1) / TPB), dim3(TPB), 0, stream>>>(ri, sdt, s1, C2, el, hdr, S, (float*)d_out);
}